// Round 7
// baseline (284.953 us; speedup 1.0000x reference)
//
#include <hip/hip_runtime.h>
#include <hip/hip_bf16.h>

// TupleAveragePredictor: out = sigmoid( relu( [mean(gnn_h[tuples[:,1:]]), gnn_h[triplets[:,2]]] @ W1^T + b1 ) @ W2^T + b2 )
// R7: mixed-precision x-tile. Avg half (fp8-sourced) stored fp8 in LDS and
// consumed by mfma_f32_16x16x32_fp8_fp8 with fp8-packed W1[:, :256];
// tgt half stays bf16 (accuracy). LDS 70.7->54.5 KB, W1 L2 stream 1.6->1.2 GB,
// A-frag LDS bytes -37%. Structure else = R6 (BM=64, 8 waves, packed W1).

#define NROWS 200000
#define NNODES 100000
#define INF 256
#define KDIM 512
#define HF 512
#define BM 64

typedef __attribute__((ext_vector_type(8))) short short8;
typedef __attribute__((ext_vector_type(4))) float f32x4;
typedef __attribute__((ext_vector_type(2))) float f32x2;

__device__ __align__(16) unsigned short g_hb[NNODES * INF];   // 51.2 MB bf16 (target reads)
__device__ __align__(16) unsigned char  g_h8[NNODES * INF];   // 25.6 MB fp8 e4m3 (avg reads)
__device__ __align__(16) unsigned char  g_W1a8p[HF * (KDIM / 2)];   // 128 KB fp8-packed W1[:, :256]
__device__ __align__(16) unsigned short g_W1bbp[HF * (KDIM / 2)];   // 256 KB bf16-packed W1[:, 256:]

__device__ __forceinline__ unsigned short f2bf(float f) {
    unsigned int u = __float_as_uint(f);
    return (unsigned short)((u + 0x7fffu + ((u >> 16) & 1u)) >> 16);
}
__device__ __forceinline__ unsigned long long pk4(float a, float b, float c, float d) {
    return (unsigned long long)f2bf(a) | ((unsigned long long)f2bf(b) << 16)
         | ((unsigned long long)f2bf(c) << 32) | ((unsigned long long)f2bf(d) << 48);
}

// gnn_h fp32 -> bf16 table AND fp8 table, 8 elems/thread (12500 blocks x 256).
__global__ void convert_h_kernel(const float* __restrict__ gnn_h) {
    int i = (blockIdx.x * 256 + threadIdx.x) * 8;
    float4 a = *(const float4*)(gnn_h + i);
    float4 b = *(const float4*)(gnn_h + i + 4);
    ulonglong2 v;
    v.x = pk4(a.x, a.y, a.z, a.w);
    v.y = pk4(b.x, b.y, b.z, b.w);
    *(ulonglong2*)(g_hb + i) = v;
    int w0 = __builtin_amdgcn_cvt_pk_fp8_f32(a.x, a.y, 0, 0);
    w0     = __builtin_amdgcn_cvt_pk_fp8_f32(a.z, a.w, w0, 1);
    int w1 = __builtin_amdgcn_cvt_pk_fp8_f32(b.x, b.y, 0, 0);
    w1     = __builtin_amdgcn_cvt_pk_fp8_f32(b.z, b.w, w1, 1);
    *(uint2*)(g_h8 + i) = make_uint2((unsigned)w0, (unsigned)w1);
}

// W1 -> two fragment-packed tables.
// chunk = cg*8 + kq (cg=col-tile 0..31, kq=k-step 0..7); within chunk,
// lane holds 8 contiguous k: col = cg*16+(lane&15), k = kq*32+(lane>>4)*8.
// fp8 table covers k in [0,256); bf16 table covers k in [256,512).
__global__ void pack_w1_kernel(const float* __restrict__ W1) {
    int tid = blockIdx.x * 256 + threadIdx.x;       // 32768 threads
    int half = tid >> 14;                            // 0: fp8, 1: bf16
    int idx  = tid & 16383;
    int chunk = idx >> 6;
    int lane  = idx & 63;
    int col = (chunk >> 3) * 16 + (lane & 15);
    int k   = (chunk & 7) * 32 + (lane >> 4) * 8;
    if (half == 0) {
        const float4 v0 = *(const float4*)(W1 + col * KDIM + k);
        const float4 v1 = *(const float4*)(W1 + col * KDIM + k + 4);
        int w0 = __builtin_amdgcn_cvt_pk_fp8_f32(v0.x, v0.y, 0, 0);
        w0     = __builtin_amdgcn_cvt_pk_fp8_f32(v0.z, v0.w, w0, 1);
        int w1 = __builtin_amdgcn_cvt_pk_fp8_f32(v1.x, v1.y, 0, 0);
        w1     = __builtin_amdgcn_cvt_pk_fp8_f32(v1.z, v1.w, w1, 1);
        *(uint2*)(g_W1a8p + chunk * 512 + lane * 8) = make_uint2((unsigned)w0, (unsigned)w1);
    } else {
        const float4 v0 = *(const float4*)(W1 + col * KDIM + 256 + k);
        const float4 v1 = *(const float4*)(W1 + col * KDIM + 256 + k + 4);
        ulonglong2 p;
        p.x = pk4(v0.x, v0.y, v0.z, v0.w);
        p.y = pk4(v1.x, v1.y, v1.z, v1.w);
        *(ulonglong2*)(g_W1bbp + chunk * 512 + lane * 8) = p;
    }
}

__global__ __launch_bounds__(512, 4)
void fused_kernel(const int* __restrict__ tuples,
                  const int* __restrict__ triplets,
                  const float* __restrict__ b1,
                  const float* __restrict__ W2,
                  const float* __restrict__ b2,
                  float* __restrict__ out) {
    __shared__ __align__(16) unsigned char  xa_lds[BM * 256];   // 16 KB fp8 avg half
    __shared__ __align__(16) unsigned short xb_lds[BM * 256];   // 32 KB bf16 tgt half
    __shared__ int idx_lds[BM * 11];
    __shared__ int tgt_lds[BM];
    __shared__ float red[8][BM];

    const int t = threadIdx.x;
    const int g0 = blockIdx.x * BM;
    const int lane = t & 63;
    const int wc = t >> 6;

    // ---- stage indices ----
    for (int i = t; i < BM * 11; i += 512) idx_lds[i] = tuples[g0 * 11 + i];
    if (t < BM) tgt_lds[t] = triplets[(g0 + t) * 3 + 2];
    __syncthreads();

    // ---- gather: 16 rows/step (32 lanes per row), 4 steps ----
    // avg (fp8 table, 8B/lane) -> fp8 LDS tile, swizzle phys = L ^ ((r&15)<<3)
    // tgt (bf16 table, 16B/lane) -> bf16 LDS tile, swizzle phys = L ^ ((r&7)<<4)
    const int rgrp = t >> 5;
    const int l32 = t & 31;
    for (int step = 0; step < BM / 16; ++step) {
        const int r = step * 16 + rgrp;
        uint2 u[10];
        #pragma unroll
        for (int i = 0; i < 10; ++i) {
            int node = idx_lds[r * 11 + 1 + i];
            node = min(max(node, 0), NNODES - 1);
            u[i] = *(const uint2*)(g_h8 + node * INF + l32 * 8);
        }
        int tg = tgt_lds[r];
        tg = min(max(tg, 0), NNODES - 1);
        const short8 ut = *(const short8*)(g_hb + tg * INF + l32 * 8);

        f32x2 s0 = {0.f, 0.f}, s1 = {0.f, 0.f}, s2 = {0.f, 0.f}, s3 = {0.f, 0.f};
        #pragma unroll
        for (int i = 0; i < 10; ++i) {
            s0 += __builtin_amdgcn_cvt_pk_f32_fp8((int)u[i].x, 0);
            s1 += __builtin_amdgcn_cvt_pk_f32_fp8((int)u[i].x, 1);
            s2 += __builtin_amdgcn_cvt_pk_f32_fp8((int)u[i].y, 0);
            s3 += __builtin_amdgcn_cvt_pk_f32_fp8((int)u[i].y, 1);
        }
        int w0 = __builtin_amdgcn_cvt_pk_fp8_f32(s0.x * 0.1f, s0.y * 0.1f, 0, 0);
        w0     = __builtin_amdgcn_cvt_pk_fp8_f32(s1.x * 0.1f, s1.y * 0.1f, w0, 1);
        int w1 = __builtin_amdgcn_cvt_pk_fp8_f32(s2.x * 0.1f, s2.y * 0.1f, 0, 0);
        w1     = __builtin_amdgcn_cvt_pk_fp8_f32(s3.x * 0.1f, s3.y * 0.1f, w1, 1);

        const int ba = (r * 256 + l32 * 8)  ^ ((r & 15) << 3);
        const int bb = (r * 512 + l32 * 16) ^ ((r & 7) << 4);
        *(uint2*)((char*)xa_lds + ba) = make_uint2((unsigned)w0, (unsigned)w1);
        *(short8*)((char*)xb_lds + bb) = ut;
    }
    __syncthreads();

    // ---- MFMA: wave wc owns h-cols [wc*64, wc*64+64), acc[4][4] ----
    const int arow = lane & 15;
    const int kgrp = lane >> 4;

    float b1r[4], w2r[4];
    #pragma unroll
    for (int ct = 0; ct < 4; ++ct) {
        b1r[ct] = b1[wc * 64 + ct * 16 + arow];
        w2r[ct] = W2[wc * 64 + ct * 16 + arow];
    }

    f32x4 acc[4][4];
    #pragma unroll
    for (int rt = 0; rt < 4; ++rt)
        #pragma unroll
        for (int ct = 0; ct < 4; ++ct)
            acc[rt][ct] = (f32x4){0.f, 0.f, 0.f, 0.f};

    const int xsw8 = arow << 3;          // (row&15)<<3, row&15 == arow
    const int xswb = (arow & 7) << 4;    // bf16 tile swizzle

    // fp8 half: k in [0,256), 8 k-steps of 32
    for (int kq = 0; kq < 8; ++kq) {
        long a8[4];
        #pragma unroll
        for (int rt = 0; rt < 4; ++rt) {
            const int loff = (rt * 16 + arow) * 256 + kq * 32 + kgrp * 8;
            a8[rt] = *(const long*)((const char*)xa_lds + (loff ^ xsw8));
        }
        #pragma unroll
        for (int ct = 0; ct < 4; ++ct) {
            const long b8 = *(const long*)(g_W1a8p + ((wc * 4 + ct) * 8 + kq) * 512 + lane * 8);
            #pragma unroll
            for (int rt = 0; rt < 4; ++rt)
                acc[rt][ct] = __builtin_amdgcn_mfma_f32_16x16x32_fp8_fp8(a8[rt], b8, acc[rt][ct], 0, 0, 0);
        }
    }
    // bf16 half: k in [256,512), 8 k-steps of 32
    for (int kq = 0; kq < 8; ++kq) {
        short8 ab[4];
        #pragma unroll
        for (int rt = 0; rt < 4; ++rt) {
            const int loff = (rt * 16 + arow) * 512 + kq * 64 + kgrp * 16;
            ab[rt] = *(const short8*)((const char*)xb_lds + (loff ^ xswb));
        }
        #pragma unroll
        for (int ct = 0; ct < 4; ++ct) {
            const short8 bb = *(const short8*)(g_W1bbp + ((wc * 4 + ct) * 8 + kq) * 512 + lane * 8);
            #pragma unroll
            for (int rt = 0; rt < 4; ++rt)
                acc[rt][ct] = __builtin_amdgcn_mfma_f32_16x16x32_bf16(ab[rt], bb, acc[rt][ct], 0, 0, 0);
        }
    }

    // ---- epilogue: relu + dot(W2) + reduce + sigmoid ----
    // D mapping: col = wc*64 + ct*16 + (lane&15), row = rt*16 + kgrp*4 + reg
    #pragma unroll
    for (int rt = 0; rt < 4; ++rt) {
        #pragma unroll
        for (int reg = 0; reg < 4; ++reg) {
            float s = 0.f;
            #pragma unroll
            for (int ct = 0; ct < 4; ++ct) {
                float h = acc[rt][ct][reg] + b1r[ct];
                s += fmaxf(h, 0.f) * w2r[ct];
            }
            s += __shfl_xor(s, 1, 64);
            s += __shfl_xor(s, 2, 64);
            s += __shfl_xor(s, 4, 64);
            s += __shfl_xor(s, 8, 64);
            if ((lane & 15) == 0)
                red[wc][rt * 16 + kgrp * 4 + reg] = s;
        }
    }
    __syncthreads();

    if (t < BM) {
        float s = b2[0];
        #pragma unroll
        for (int i = 0; i < 8; ++i) s += red[i][t];
        out[g0 + t] = 1.f / (1.f + expf(-s));
    }
}

extern "C" void kernel_launch(void* const* d_in, const int* in_sizes, int n_in,
                              void* d_out, int out_size, void* d_ws, size_t ws_size,
                              hipStream_t stream) {
    const float* gnn_h    = (const float*)d_in[0];
    const int*   tuples   = (const int*)d_in[1];
    const int*   triplets = (const int*)d_in[2];
    const float* W1       = (const float*)d_in[3];
    const float* b1       = (const float*)d_in[4];
    const float* W2       = (const float*)d_in[5];
    const float* b2       = (const float*)d_in[6];
    float* out = (float*)d_out;

    convert_h_kernel<<<dim3(NNODES * INF / (256 * 8)), dim3(256), 0, stream>>>(gnn_h);
    pack_w1_kernel<<<dim3(128), dim3(256), 0, stream>>>(W1);
    fused_kernel<<<dim3(NROWS / BM), dim3(512), 0, stream>>>(
        tuples, triplets, b1, W2, b2, out);
}

// Round 8
// 253.484 us; speedup vs baseline: 1.1241x; 1.1241x over previous
//
#include <hip/hip_runtime.h>
#include <hip/hip_bf16.h>

// TupleAveragePredictor: out = sigmoid( relu( [mean(gnn_h[tuples[:,1:]]), gnn_h[triplets[:,2]]] @ W1^T + b1 ) @ W2^T + b2 )
// R8 = R6 (proven 245us) + fatter gather: dwordx4 16B/lane, 16 lanes per fp8
// row, 4 rows per wave-instr -> gather vmem instrs 44->24 per wave (same
// bytes). MFMA phase / LDS layout / swizzle identical to R6. fp8 decode in
// two 5-node batches to stay under the 64-VGPR cap (R7 lesson: spill shows
// as WRITE_SIZE balloon).

#define NROWS 200000
#define NNODES 100000
#define INF 256
#define KDIM 512
#define HF 512
#define BM 64

typedef __attribute__((ext_vector_type(8))) short short8;
typedef __attribute__((ext_vector_type(4))) float f32x4;
typedef __attribute__((ext_vector_type(2))) float f32x2;

__device__ __align__(16) unsigned short g_hb[NNODES * INF];   // 51.2 MB bf16 (target reads)
__device__ __align__(16) unsigned char  g_h8[NNODES * INF];   // 25.6 MB fp8 e4m3 (avg reads)
__device__ __align__(16) unsigned short g_W1p[HF * KDIM];     // 512 KB fragment-packed W1

__device__ __forceinline__ unsigned short f2bf(float f) {
    unsigned int u = __float_as_uint(f);
    return (unsigned short)((u + 0x7fffu + ((u >> 16) & 1u)) >> 16);
}
__device__ __forceinline__ unsigned long long pk4(float a, float b, float c, float d) {
    return (unsigned long long)f2bf(a) | ((unsigned long long)f2bf(b) << 16)
         | ((unsigned long long)f2bf(c) << 32) | ((unsigned long long)f2bf(d) << 48);
}

// gnn_h fp32 -> bf16 table AND fp8 table, 8 elems/thread (12500 blocks x 256).
__global__ void convert_h_kernel(const float* __restrict__ gnn_h) {
    int i = (blockIdx.x * 256 + threadIdx.x) * 8;
    float4 a = *(const float4*)(gnn_h + i);
    float4 b = *(const float4*)(gnn_h + i + 4);
    ulonglong2 v;
    v.x = pk4(a.x, a.y, a.z, a.w);
    v.y = pk4(b.x, b.y, b.z, b.w);
    *(ulonglong2*)(g_hb + i) = v;
    int w0 = __builtin_amdgcn_cvt_pk_fp8_f32(a.x, a.y, 0, 0);
    w0     = __builtin_amdgcn_cvt_pk_fp8_f32(a.z, a.w, w0, 1);
    int w1 = __builtin_amdgcn_cvt_pk_fp8_f32(b.x, b.y, 0, 0);
    w1     = __builtin_amdgcn_cvt_pk_fp8_f32(b.z, b.w, w1, 1);
    *(uint2*)(g_h8 + i) = make_uint2((unsigned)w0, (unsigned)w1);
}

// W1 -> bf16 packed in B-fragment order (as R5/R6):
// packed[(c*16+ki)*512 + lane*8 + j] = W1[col=c*16+(lane&15)][k=ki*32+(lane>>4)*8+j]
__global__ void pack_w1_kernel(const float* __restrict__ W1) {
    int p = (blockIdx.x * 256 + threadIdx.x) * 4;  // 262144/4 = 65536 thr
    int chunk  = p >> 9;
    int within = p & 511;
    int lane = within >> 3;
    int j0   = within & 7;
    int c  = chunk >> 4, ki = chunk & 15;
    int col = c * 16 + (lane & 15);
    int k   = ki * 32 + (lane >> 4) * 8 + j0;
    float4 v = *(const float4*)(W1 + col * KDIM + k);
    *(unsigned long long*)(g_W1p + p) = pk4(v.x, v.y, v.z, v.w);
}

__global__ __launch_bounds__(512, 4)
void fused_kernel(const int* __restrict__ tuples,
                  const int* __restrict__ triplets,
                  const float* __restrict__ b1,
                  const float* __restrict__ W2,
                  const float* __restrict__ b2,
                  float* __restrict__ out) {
    __shared__ __align__(16) unsigned short x_lds[BM * KDIM];  // 64 KB, swizzled
    __shared__ int idx_lds[BM * 11];
    __shared__ int tgt_lds[BM];
    __shared__ float red[8][BM];

    const int t = threadIdx.x;
    const int g0 = blockIdx.x * BM;
    const int lane = t & 63;
    const int wc = t >> 6;

    // ---- stage indices ----
    for (int i = t; i < BM * 11; i += 512) idx_lds[i] = tuples[g0 * 11 + i];
    if (t < BM) tgt_lds[t] = triplets[(g0 + t) * 3 + 2];
    __syncthreads();

    // ---- gather phase A: averaged half, 4 rows per wave-instr ----
    // lane = sub(row, bits 5:4) | l16(col segment, bits 3:0); 16B fp8 per lane.
    // swizzled LDS: phys = L ^ ((row&7)<<4), L = row*1024 + col*2
    const int sub = lane >> 4;
    const int l16 = lane & 15;
    for (int step = 0; step < 2; ++step) {
        const int r = step * 32 + wc * 4 + sub;
        float sacc[16];
        #pragma unroll
        for (int q = 0; q < 16; ++q) sacc[q] = 0.f;
        #pragma unroll
        for (int half = 0; half < 2; ++half) {
            uint4 u[5];
            #pragma unroll
            for (int i = 0; i < 5; ++i) {
                int node = idx_lds[r * 11 + 1 + half * 5 + i];
                node = min(max(node, 0), NNODES - 1);
                u[i] = *(const uint4*)(g_h8 + node * INF + l16 * 16);
            }
            #pragma unroll
            for (int i = 0; i < 5; ++i) {
                const unsigned* d = &u[i].x;
                #pragma unroll
                for (int q = 0; q < 4; ++q) {
                    f32x2 lo = __builtin_amdgcn_cvt_pk_f32_fp8((int)d[q], 0);
                    f32x2 hi = __builtin_amdgcn_cvt_pk_f32_fp8((int)d[q], 1);
                    sacc[q * 4 + 0] += lo.x; sacc[q * 4 + 1] += lo.y;
                    sacc[q * 4 + 2] += hi.x; sacc[q * 4 + 3] += hi.y;
                }
            }
        }
        ulonglong2 p0, p1;
        p0.x = pk4(sacc[0]  * 0.1f, sacc[1]  * 0.1f, sacc[2]  * 0.1f, sacc[3]  * 0.1f);
        p0.y = pk4(sacc[4]  * 0.1f, sacc[5]  * 0.1f, sacc[6]  * 0.1f, sacc[7]  * 0.1f);
        p1.x = pk4(sacc[8]  * 0.1f, sacc[9]  * 0.1f, sacc[10] * 0.1f, sacc[11] * 0.1f);
        p1.y = pk4(sacc[12] * 0.1f, sacc[13] * 0.1f, sacc[14] * 0.1f, sacc[15] * 0.1f);
        const int x = (r & 7) << 4;
        const int L0 = r * 1024 + l16 * 32;
        *(ulonglong2*)((char*)x_lds + (L0 ^ x)) = p0;
        *(ulonglong2*)((char*)x_lds + ((L0 + 16) ^ x)) = p1;
    }

    // ---- gather phase B: target half, 2 rows per wave-instr (as R6) ----
    const int l32 = lane & 31;
    const int rhalf = lane >> 5;
    #pragma unroll
    for (int j = 0; j < 4; ++j) {
        const int r = wc * 8 + j * 2 + rhalf;
        int tg = tgt_lds[r];
        tg = min(max(tg, 0), NNODES - 1);
        const short8 ut = *(const short8*)(g_hb + tg * INF + l32 * 8);
        const int x = (r & 7) << 4;
        *(short8*)((char*)x_lds + ((r * 1024 + 512 + l32 * 16) ^ x)) = ut;
    }
    __syncthreads();

    // ---- MFMA: wave wc owns h-cols [wc*64, wc*64+64), acc[4][4] (= R6) ----
    const int arow = lane & 15;
    const int kgrp = lane >> 4;

    float b1r[4], w2r[4];
    #pragma unroll
    for (int ct = 0; ct < 4; ++ct) {
        b1r[ct] = b1[wc * 64 + ct * 16 + arow];
        w2r[ct] = W2[wc * 64 + ct * 16 + arow];
    }

    f32x4 acc[4][4];
    #pragma unroll
    for (int rt = 0; rt < 4; ++rt)
        #pragma unroll
        for (int ct = 0; ct < 4; ++ct)
            acc[rt][ct] = (f32x4){0.f, 0.f, 0.f, 0.f};

    const int xsw = (arow & 7) << 4;
    for (int ki = 0; ki < 16; ++ki) {
        short8 a[4];
        #pragma unroll
        for (int rt = 0; rt < 4; ++rt) {
            const int loff = (rt * 16 + arow) * 1024 + ki * 64 + kgrp * 16;
            a[rt] = *(const short8*)((const char*)x_lds + (loff ^ xsw));
        }
        #pragma unroll
        for (int ct = 0; ct < 4; ++ct) {
            const short8 b = *(const short8*)(g_W1p + ((wc * 4 + ct) * 16 + ki) * 512 + lane * 8);
            #pragma unroll
            for (int rt = 0; rt < 4; ++rt)
                acc[rt][ct] = __builtin_amdgcn_mfma_f32_16x16x32_bf16(a[rt], b, acc[rt][ct], 0, 0, 0);
        }
    }

    // ---- epilogue: relu + dot(W2) + reduce + sigmoid ----
    // D mapping: col = wc*64 + ct*16 + (lane&15), row = rt*16 + kgrp*4 + reg
    #pragma unroll
    for (int rt = 0; rt < 4; ++rt) {
        #pragma unroll
        for (int reg = 0; reg < 4; ++reg) {
            float s = 0.f;
            #pragma unroll
            for (int ct = 0; ct < 4; ++ct) {
                float h = acc[rt][ct][reg] + b1r[ct];
                s += fmaxf(h, 0.f) * w2r[ct];
            }
            s += __shfl_xor(s, 1, 64);
            s += __shfl_xor(s, 2, 64);
            s += __shfl_xor(s, 4, 64);
            s += __shfl_xor(s, 8, 64);
            if ((lane & 15) == 0)
                red[wc][rt * 16 + kgrp * 4 + reg] = s;
        }
    }
    __syncthreads();

    if (t < BM) {
        float s = b2[0];
        #pragma unroll
        for (int i = 0; i < 8; ++i) s += red[i][t];
        out[g0 + t] = 1.f / (1.f + expf(-s));
    }
}

extern "C" void kernel_launch(void* const* d_in, const int* in_sizes, int n_in,
                              void* d_out, int out_size, void* d_ws, size_t ws_size,
                              hipStream_t stream) {
    const float* gnn_h    = (const float*)d_in[0];
    const int*   tuples   = (const int*)d_in[1];
    const int*   triplets = (const int*)d_in[2];
    const float* W1       = (const float*)d_in[3];
    const float* b1       = (const float*)d_in[4];
    const float* W2       = (const float*)d_in[5];
    const float* b2       = (const float*)d_in[6];
    float* out = (float*)d_out;

    convert_h_kernel<<<dim3(NNODES * INF / (256 * 8)), dim3(256), 0, stream>>>(gnn_h);
    pack_w1_kernel<<<dim3(HF * KDIM / (256 * 4)), dim3(256), 0, stream>>>(W1);
    fused_kernel<<<dim3(NROWS / BM), dim3(512), 0, stream>>>(
        tuples, triplets, b1, W2, b2, out);
}